// Round 1
// baseline (822.152 us; speedup 1.0000x reference)
//
#include <hip/hip_runtime.h>
#include <hip/hip_fp16.h>
#include <math.h>

// Net_76854144794847: GSDN dense-graph diffusion GCN. fp32 in / fp32 out.
// dur model: ~640us fixed harness poison fills + ~60-110us compute.
// R5 lesson: coop grid.sync() ~200us/barrier on MI355X -> per-step launches
//            for layer-1 (meaty kernels), but layer-2 steps are tiny and
//            launch-overhead dominated -> single persistent kernel with a
//            256-block custom barrier (co-residency trivially guaranteed).
#define N_NODES 8192
#define F_IN    512
#define HID     128
#define NCLS    16
#define MAX_ELL 256
#define C_RES   0.5555555555555556f   // 1/(1+alpha), alpha=0.8
#define C_PROP  0.4444444444444445f   // alpha/(1+alpha)

#define P2_BLOCKS 256
#define P2_ROWSPB 32                  // rows per block in persistent layer-2

typedef unsigned short u16;

__device__ __forceinline__ float4 ld_h4(const __half* p) {
    const uint2 u = *reinterpret_cast<const uint2*>(p);
    const __half2 h0 = *reinterpret_cast<const __half2*>(&u.x);
    const __half2 h1 = *reinterpret_cast<const __half2*>(&u.y);
    const float2 f0 = __half22float2(h0);
    const float2 f1 = __half22float2(h1);
    return make_float4(f0.x, f0.y, f1.x, f1.y);
}
__device__ __forceinline__ void st_h4(__half* p, float4 v) {
    __half2 h0 = __floats2half2_rn(v.x, v.y);
    __half2 h1 = __floats2half2_rn(v.z, v.w);
    uint2 u;
    u.x = *reinterpret_cast<unsigned int*>(&h0);
    u.y = *reinterpret_cast<unsigned int*>(&h1);
    *reinterpret_cast<uint2*>(p) = u;
}
__device__ __forceinline__ void add4(float4& a, const float4 b) {
    a.x += b.x; a.y += b.y; a.z += b.z; a.w += b.w;
}

// ---------------------------------------------------------------------------
// K1 (fused): blocks 0..255 = GEMM1 (h1 = x@W1); blocks 256..8447 = adjacency
// scan (1 row/block). GEMM blocks dispatch first, hide under the 268 MB
// HBM-bound scan (~41us floor).
// ---------------------------------------------------------------------------
__global__ __launch_bounds__(256) void scan_gemm_kernel(
    const float* __restrict__ adj, const float* __restrict__ x,
    const float* __restrict__ W1,
    u16* __restrict__ ell, int* __restrict__ nnz,
    float* __restrict__ dinv, float* __restrict__ arow,
    float* __restrict__ h1)
{
    if (blockIdx.x < 256) {
        const int tx = threadIdx.x & 31;
        const int ty = threadIdx.x >> 5;
        const int c  = tx * 4;
        const int r0 = blockIdx.x * 32 + ty * 4;
        const float4* W4 = reinterpret_cast<const float4*>(W1);
        const float4* xr[4];
        #pragma unroll
        for (int i = 0; i < 4; ++i)
            xr[i] = reinterpret_cast<const float4*>(x + (size_t)(r0 + i) * F_IN);
        float4 acc[4] = {{0,0,0,0},{0,0,0,0},{0,0,0,0},{0,0,0,0}};
        #pragma unroll 2
        for (int kk = 0; kk < F_IN / 4; ++kk) {
            const int k = kk * 4;
            const float4 w0 = W4[(size_t)(k + 0) * 32 + tx];
            const float4 w1 = W4[(size_t)(k + 1) * 32 + tx];
            const float4 w2 = W4[(size_t)(k + 2) * 32 + tx];
            const float4 w3 = W4[(size_t)(k + 3) * 32 + tx];
            #pragma unroll
            for (int i = 0; i < 4; ++i) {
                const float4 xv = xr[i][kk];
                acc[i].x = fmaf(xv.x, w0.x, acc[i].x);
                acc[i].y = fmaf(xv.x, w0.y, acc[i].y);
                acc[i].z = fmaf(xv.x, w0.z, acc[i].z);
                acc[i].w = fmaf(xv.x, w0.w, acc[i].w);
                acc[i].x = fmaf(xv.y, w1.x, acc[i].x);
                acc[i].y = fmaf(xv.y, w1.y, acc[i].y);
                acc[i].z = fmaf(xv.y, w1.z, acc[i].z);
                acc[i].w = fmaf(xv.y, w1.w, acc[i].w);
                acc[i].x = fmaf(xv.z, w2.x, acc[i].x);
                acc[i].y = fmaf(xv.z, w2.y, acc[i].y);
                acc[i].z = fmaf(xv.z, w2.z, acc[i].z);
                acc[i].w = fmaf(xv.z, w2.w, acc[i].w);
                acc[i].x = fmaf(xv.w, w3.x, acc[i].x);
                acc[i].y = fmaf(xv.w, w3.y, acc[i].y);
                acc[i].z = fmaf(xv.w, w3.z, acc[i].z);
                acc[i].w = fmaf(xv.w, w3.w, acc[i].w);
            }
        }
        #pragma unroll
        for (int i = 0; i < 4; ++i)
            *reinterpret_cast<float4*>(h1 + (size_t)(r0 + i) * HID + c) = acc[i];
    } else {
        const int r = blockIdx.x - 256;
        __shared__ int cnt;
        if (threadIdx.x == 0) cnt = 0;
        __syncthreads();
        const uint4* row4 = reinterpret_cast<const uint4*>(adj + (size_t)r * N_NODES);
        u16* __restrict__ erow = ell + (size_t)r * MAX_ELL;
        for (int b = threadIdx.x; b < N_NODES / 4; b += blockDim.x) {
            const uint4 v = row4[b];
            const int base = b * 4;
            if (v.x) { int p = atomicAdd(&cnt, 1); if (p < MAX_ELL) erow[p] = (u16)(base + 0); }
            if (v.y) { int p = atomicAdd(&cnt, 1); if (p < MAX_ELL) erow[p] = (u16)(base + 1); }
            if (v.z) { int p = atomicAdd(&cnt, 1); if (p < MAX_ELL) erow[p] = (u16)(base + 2); }
            if (v.w) { int p = atomicAdd(&cnt, 1); if (p < MAX_ELL) erow[p] = (u16)(base + 3); }
        }
        __syncthreads();
        if (threadIdx.x == 0) {
            int c = cnt; if (c > MAX_ELL) c = MAX_ELL;
            nnz[r] = c;
            const float di = rsqrtf((float)cnt + 1.0f);
            dinv[r] = di;
            arow[r] = C_PROP * di * di;
        }
    }
}

// ---------------------------------------------------------------------------
// K2: s0 = dinv*h1 (fp16), hb = cres*dinv*h1 (fp32). Elementwise.
// Also zeroes the persistent-kernel barrier counters (runs well before P2;
// the kernel boundary guarantees visibility).
// ---------------------------------------------------------------------------
__global__ __launch_bounds__(256) void prep1_kernel(
    const float* __restrict__ h1, const float* __restrict__ dinv,
    __half* __restrict__ s0, float* __restrict__ hb,
    unsigned* __restrict__ bar)
{
    if (blockIdx.x == 0 && threadIdx.x < 16) bar[threadIdx.x] = 0u;
    const int tx = threadIdx.x & 31;
    const int r  = blockIdx.x * 8 + (threadIdx.x >> 5);
    const int c  = tx * 4;
    const size_t o = (size_t)r * HID + c;
    const float di = dinv[r];
    const float4 hv = *reinterpret_cast<const float4*>(h1 + o);
    float4 sv = make_float4(di * hv.x, di * hv.y, di * hv.z, di * hv.w);
    st_h4(s0 + o, sv);
    *reinterpret_cast<float4*>(hb + o) =
        make_float4(C_RES * sv.x, C_RES * sv.y, C_RES * sv.z, C_RES * sv.w);
}

// ---------------------------------------------------------------------------
// K3: layer-1 diffusion step, prescaled fp16 space, 4-way unrolled gathers.
// thread = 1 row x 4 cols; 32 lanes/row; 8 rows/block. L2-BW bound (~136 MB
// gather traffic/step at ~34 TB/s) -> kept as per-step launches.
// ---------------------------------------------------------------------------
__global__ __launch_bounds__(256) void diffuse1_kernel(
    const __half* __restrict__ sin, const float* __restrict__ hb,
    __half* __restrict__ sout,
    const u16* __restrict__ ell, const int* __restrict__ nnz,
    const float* __restrict__ arow)
{
    const int tx = threadIdx.x & 31;
    const int r  = blockIdx.x * 8 + (threadIdx.x >> 5);
    const int c  = tx * 4;
    const int nn = nnz[r];
    const u16* __restrict__ erow = ell + (size_t)r * MAX_ELL;

    const float4 hv = *reinterpret_cast<const float4*>(hb + (size_t)r * HID + c);
    float4 a0 = ld_h4(sin + (size_t)r * HID + c);   // self term
    float4 a1 = {0,0,0,0}, a2 = {0,0,0,0}, a3 = {0,0,0,0};
    int t = 0;
    for (; t + 4 <= nn; t += 4) {
        const int j0 = erow[t + 0];
        const int j1 = erow[t + 1];
        const int j2 = erow[t + 2];
        const int j3 = erow[t + 3];
        const float4 g0 = ld_h4(sin + (size_t)j0 * HID + c);
        const float4 g1 = ld_h4(sin + (size_t)j1 * HID + c);
        const float4 g2 = ld_h4(sin + (size_t)j2 * HID + c);
        const float4 g3 = ld_h4(sin + (size_t)j3 * HID + c);
        add4(a0, g0); add4(a1, g1); add4(a2, g2); add4(a3, g3);
    }
    for (; t < nn; ++t) add4(a1, ld_h4(sin + (size_t)erow[t] * HID + c));
    add4(a0, a1); add4(a2, a3); add4(a0, a2);

    const float Ai = arow[r];
    float4 s = make_float4(fmaf(Ai, a0.x, hv.x), fmaf(Ai, a0.y, hv.y),
                           fmaf(Ai, a0.z, hv.z), fmaf(Ai, a0.w, hv.w));
    st_h4(sout + (size_t)r * HID + c, s);
}

// ---------------------------------------------------------------------------
// K4 (merged final1 + gemm2): per row r,
//   o1_c = relu(cprop*dinv_r*G_c + cres*h1_c + b1_c)     (kept in regs)
//   h2[r][:] = o1_row @ W2  via per-lane partials + 5-step shfl_xor butterfly
// Epilogue lanes 0..15 write h2, s2 = dinv*h2, hb2 = cres*dinv*h2.
// ---------------------------------------------------------------------------
__global__ __launch_bounds__(256) void final1_gemm_kernel(
    const __half* __restrict__ sin, const float* __restrict__ h1,
    const float* __restrict__ b1, const float* __restrict__ W2,
    const u16* __restrict__ ell, const int* __restrict__ nnz,
    const float* __restrict__ dinv,
    float* __restrict__ h2, float* __restrict__ s2, float* __restrict__ hb2)
{
    const int tx = threadIdx.x & 31;
    const int r  = blockIdx.x * 8 + (threadIdx.x >> 5);
    const int c  = tx * 4;
    const int nn = nnz[r];
    const u16* __restrict__ erow = ell + (size_t)r * MAX_ELL;

    float4 a0 = ld_h4(sin + (size_t)r * HID + c);
    float4 a1 = {0,0,0,0}, a2 = {0,0,0,0}, a3 = {0,0,0,0};
    int t = 0;
    for (; t + 4 <= nn; t += 4) {
        const int j0 = erow[t + 0];
        const int j1 = erow[t + 1];
        const int j2 = erow[t + 2];
        const int j3 = erow[t + 3];
        const float4 g0 = ld_h4(sin + (size_t)j0 * HID + c);
        const float4 g1 = ld_h4(sin + (size_t)j1 * HID + c);
        const float4 g2 = ld_h4(sin + (size_t)j2 * HID + c);
        const float4 g3 = ld_h4(sin + (size_t)j3 * HID + c);
        add4(a0, g0); add4(a1, g1); add4(a2, g2); add4(a3, g3);
    }
    for (; t < nn; ++t) add4(a1, ld_h4(sin + (size_t)erow[t] * HID + c));
    add4(a0, a1); add4(a2, a3); add4(a0, a2);

    const float di = dinv[r];
    const float pd = C_PROP * di;
    const float4 hv = *reinterpret_cast<const float4*>(h1 + (size_t)r * HID + c);
    const float4 bv = *reinterpret_cast<const float4*>(b1 + c);
    float ov[4];
    ov[0] = fmaxf(fmaf(pd, a0.x, C_RES * hv.x) + bv.x, 0.f);
    ov[1] = fmaxf(fmaf(pd, a0.y, C_RES * hv.y) + bv.y, 0.f);
    ov[2] = fmaxf(fmaf(pd, a0.z, C_RES * hv.z) + bv.z, 0.f);
    ov[3] = fmaxf(fmaf(pd, a0.w, C_RES * hv.w) + bv.w, 0.f);

    // per-lane partial dot products over this lane's 4 k-indices
    float p[NCLS];
    #pragma unroll
    for (int cc = 0; cc < NCLS; ++cc) p[cc] = 0.f;
    #pragma unroll
    for (int i = 0; i < 4; ++i) {
        const float* w = W2 + (size_t)(c + i) * NCLS;
        const float v = ov[i];
        #pragma unroll
        for (int cc = 0; cc < NCLS; ++cc) p[cc] = fmaf(v, w[cc], p[cc]);
    }
    // butterfly sum across the 32 lanes of this row group
    #pragma unroll
    for (int m = 1; m <= 16; m <<= 1) {
        #pragma unroll
        for (int cc = 0; cc < NCLS; ++cc) p[cc] += __shfl_xor(p[cc], m);
    }
    if (tx < NCLS) {
        const float v = p[tx];
        const size_t o = (size_t)r * NCLS + tx;
        h2[o]  = v;
        s2[o]  = di * v;
        hb2[o] = C_RES * di * v;
    }
}

// ---------------------------------------------------------------------------
// Device-scope grid barrier for the persistent layer-2 kernel.
// One counter per phase (no sense-reversal needed; prep1 zeroes them).
// __syncthreads drains the block's stores to L2 (compiler emits vmcnt(0));
// the ACQ_REL agent-scope RMW + ACQUIRE spin handle cross-XCD L2
// writeback/invalidate, same as a kernel boundary would.
// ---------------------------------------------------------------------------
__device__ __forceinline__ void grid_bar(unsigned* bar, int phase) {
    __syncthreads();
    if (threadIdx.x == 0) {
        __hip_atomic_fetch_add(bar + phase, 1u, __ATOMIC_ACQ_REL,
                               __HIP_MEMORY_SCOPE_AGENT);
        while (__hip_atomic_load(bar + phase, __ATOMIC_ACQUIRE,
                                 __HIP_MEMORY_SCOPE_AGENT) < (unsigned)P2_BLOCKS)
            __builtin_amdgcn_s_sleep(1);
    }
    __syncthreads();
}

// ---------------------------------------------------------------------------
// K5 (persistent): entire layer-2 = 7 diffusion steps + final + log_softmax
// in ONE launch. 256 blocks x 128 threads (2 waves/CU on 256 CUs ->
// co-residency guaranteed). 4 lanes/row x 32 rows/block. ELL rows cached in
// LDS once (u16) and reused across all 8 applications; hb2/arow/nnz pinned
// in registers. Replaces 8 launch-overhead-dominated dispatches.
// ---------------------------------------------------------------------------
__global__ __launch_bounds__(128) void layer2_persist_kernel(
    float* __restrict__ s2A, float* __restrict__ s2B,
    const float* __restrict__ hb2, const float* __restrict__ h2,
    const float* __restrict__ b2, float* __restrict__ out,
    const u16* __restrict__ ell, const int* __restrict__ nnz,
    const float* __restrict__ dinv, const float* __restrict__ arow,
    unsigned* __restrict__ bar)
{
    __shared__ u16 lell[P2_ROWSPB][MAX_ELL];
    const int tid = threadIdx.x;
    const int rr  = tid >> 2;                       // local row 0..31
    const int l4  = tid & 3;
    const int r   = blockIdx.x * P2_ROWSPB + rr;
    const int c   = l4 * 4;
    const int nn  = nnz[r];

    // cache this row's neighbor list in LDS (4 lanes/row cooperate)
    {
        const u16* __restrict__ erow = ell + (size_t)r * MAX_ELL;
        for (int t = l4; t < nn; t += 4) lell[rr][t] = erow[t];
    }
    const float  Ai  = arow[r];
    const float4 hbv = *reinterpret_cast<const float4*>(hb2 + (size_t)r * NCLS + c);
    __syncthreads();

    const float* cur = s2A;
    float* bufs[2] = { s2B, s2A };
    for (int s = 0; s < 7; ++s) {
        float* dst = bufs[s & 1];
        float4 a0 = *reinterpret_cast<const float4*>(cur + (size_t)r * NCLS + c);
        float4 a1 = {0,0,0,0}, a2 = {0,0,0,0}, a3 = {0,0,0,0};
        int t = 0;
        for (; t + 4 <= nn; t += 4) {
            const int j0 = lell[rr][t + 0];
            const int j1 = lell[rr][t + 1];
            const int j2 = lell[rr][t + 2];
            const int j3 = lell[rr][t + 3];
            add4(a0, *reinterpret_cast<const float4*>(cur + (size_t)j0 * NCLS + c));
            add4(a1, *reinterpret_cast<const float4*>(cur + (size_t)j1 * NCLS + c));
            add4(a2, *reinterpret_cast<const float4*>(cur + (size_t)j2 * NCLS + c));
            add4(a3, *reinterpret_cast<const float4*>(cur + (size_t)j3 * NCLS + c));
        }
        for (; t < nn; ++t)
            add4(a1, *reinterpret_cast<const float4*>(cur + (size_t)lell[rr][t] * NCLS + c));
        add4(a0, a1); add4(a2, a3); add4(a0, a2);

        float4 sv = make_float4(fmaf(Ai, a0.x, hbv.x), fmaf(Ai, a0.y, hbv.y),
                                fmaf(Ai, a0.z, hbv.z), fmaf(Ai, a0.w, hbv.w));
        *reinterpret_cast<float4*>(dst + (size_t)r * NCLS + c) = sv;

        grid_bar(bar, s);
        cur = dst;
    }

    // final application + bias + log_softmax
    {
        float4 a0 = *reinterpret_cast<const float4*>(cur + (size_t)r * NCLS + c);
        float4 a1 = {0,0,0,0}, a2 = {0,0,0,0}, a3 = {0,0,0,0};
        int t = 0;
        for (; t + 4 <= nn; t += 4) {
            const int j0 = lell[rr][t + 0];
            const int j1 = lell[rr][t + 1];
            const int j2 = lell[rr][t + 2];
            const int j3 = lell[rr][t + 3];
            add4(a0, *reinterpret_cast<const float4*>(cur + (size_t)j0 * NCLS + c));
            add4(a1, *reinterpret_cast<const float4*>(cur + (size_t)j1 * NCLS + c));
            add4(a2, *reinterpret_cast<const float4*>(cur + (size_t)j2 * NCLS + c));
            add4(a3, *reinterpret_cast<const float4*>(cur + (size_t)j3 * NCLS + c));
        }
        for (; t < nn; ++t)
            add4(a1, *reinterpret_cast<const float4*>(cur + (size_t)lell[rr][t] * NCLS + c));
        add4(a0, a1); add4(a2, a3); add4(a0, a2);

        const float pd = C_PROP * dinv[r];
        const float4 hv = *reinterpret_cast<const float4*>(h2 + (size_t)r * NCLS + c);
        const float4 bv = *reinterpret_cast<const float4*>(b2 + c);
        float4 o;
        o.x = fmaf(pd, a0.x, C_RES * hv.x) + bv.x;
        o.y = fmaf(pd, a0.y, C_RES * hv.y) + bv.y;
        o.z = fmaf(pd, a0.z, C_RES * hv.z) + bv.z;
        o.w = fmaf(pd, a0.w, C_RES * hv.w) + bv.w;

        float mx = fmaxf(fmaxf(o.x, o.y), fmaxf(o.z, o.w));
        mx = fmaxf(mx, __shfl_xor(mx, 1));
        mx = fmaxf(mx, __shfl_xor(mx, 2));
        float s = __expf(o.x - mx) + __expf(o.y - mx) + __expf(o.z - mx) + __expf(o.w - mx);
        s += __shfl_xor(s, 1);
        s += __shfl_xor(s, 2);
        const float lse = mx + __logf(s);
        *reinterpret_cast<float4*>(out + (size_t)r * NCLS + c) =
            make_float4(o.x - lse, o.y - lse, o.z - lse, o.w - lse);
    }
}

// ---------------------------------------------------------------------------
extern "C" void kernel_launch(void* const* d_in, const int* in_sizes, int n_in,
                              void* d_out, int out_size, void* d_ws, size_t ws_size,
                              hipStream_t stream)
{
    const float* x   = (const float*)d_in[0];
    const float* adj = (const float*)d_in[1];
    const float* W1  = (const float*)d_in[2];
    const float* b1  = (const float*)d_in[3];
    const float* W2  = (const float*)d_in[4];
    const float* b2  = (const float*)d_in[5];
    float* out = (float*)d_out;

    char* ws = (char*)d_ws;
    size_t off = 0;
    auto carve = [&](size_t bytes) -> void* {
        void* p = ws + off;
        off += (bytes + 255) & ~(size_t)255;
        return p;
    };
    u16*      ell  = (u16*)     carve((size_t)N_NODES * MAX_ELL * sizeof(u16));
    int*      nnz  = (int*)     carve((size_t)N_NODES * sizeof(int));
    float*    dinv = (float*)   carve((size_t)N_NODES * sizeof(float));
    float*    arow = (float*)   carve((size_t)N_NODES * sizeof(float));
    float*    h1   = (float*)   carve((size_t)N_NODES * HID * sizeof(float));
    float*    hb   = (float*)   carve((size_t)N_NODES * HID * sizeof(float));
    __half*   sA   = (__half*)  carve((size_t)N_NODES * HID * sizeof(__half));
    __half*   sB   = (__half*)  carve((size_t)N_NODES * HID * sizeof(__half));
    float*    h2   = (float*)   carve((size_t)N_NODES * NCLS * sizeof(float));
    float*    hb2  = (float*)   carve((size_t)N_NODES * NCLS * sizeof(float));
    float*    s2A  = (float*)   carve((size_t)N_NODES * NCLS * sizeof(float));
    float*    s2B  = (float*)   carve((size_t)N_NODES * NCLS * sizeof(float));
    unsigned* bar  = (unsigned*)carve(16 * sizeof(unsigned));

    // K1: fused adjacency scan + GEMM1 (GEMM hides under HBM-bound scan)
    scan_gemm_kernel<<<8448, 256, 0, stream>>>(adj, x, W1, ell, nnz, dinv, arow, h1);

    // K2: prep s0/hb (needs dinv -> after scan); also zeroes barrier counters
    prep1_kernel<<<N_NODES / 8, 256, 0, stream>>>(h1, dinv, sA, hb, bar);

    // layer-1: 7 fp16 diffusion steps, then merged final+gemm2
    {
        const __half* cur = sA;
        __half* bufs[2] = {sB, sA};
        for (int s = 0; s < 7; ++s) {
            __half* dst = bufs[s & 1];
            diffuse1_kernel<<<N_NODES / 8, 256, 0, stream>>>(cur, hb, dst, ell, nnz, arow);
            cur = dst;
        }
        final1_gemm_kernel<<<N_NODES / 8, 256, 0, stream>>>(
            cur, h1, b1, W2, ell, nnz, dinv, h2, s2A, hb2);
    }

    // layer-2: single persistent kernel (7 steps + final + lsm, 7 grid barriers)
    layer2_persist_kernel<<<P2_BLOCKS, 128, 0, stream>>>(
        s2A, s2B, hb2, h2, b2, out, ell, nnz, dinv, arow, bar);

    (void)in_sizes; (void)n_in; (void)out_size; (void)ws_size;
}

// Round 2
// 692.772 us; speedup vs baseline: 1.1868x; 1.1868x over previous
//
#include <hip/hip_runtime.h>
#include <hip/hip_fp16.h>
#include <math.h>

// Net_76854144794847: GSDN dense-graph diffusion GCN. fp32 in / fp32 out.
// dur model: ~640us fixed harness poison fills + ~43us HBM-bound scan + ~15us rest.
// R5 lesson: coop grid.sync() ~200us/barrier on MI355X -> per-step launches.
// R1 lesson: hand-rolled 256-block spin barrier is ~38us/barrier (L2/fabric
//            contention on the counter line) -> kernel-boundary IS the cheap
//            grid barrier; persistent layer-2 reverted. u16 ELL kept.
#define N_NODES 8192
#define F_IN    512
#define HID     128
#define NCLS    16
#define MAX_ELL 256
#define C_RES   0.5555555555555556f   // 1/(1+alpha), alpha=0.8
#define C_PROP  0.4444444444444445f   // alpha/(1+alpha)

typedef unsigned short u16;

__device__ __forceinline__ float4 ld_h4(const __half* p) {
    const uint2 u = *reinterpret_cast<const uint2*>(p);
    const __half2 h0 = *reinterpret_cast<const __half2*>(&u.x);
    const __half2 h1 = *reinterpret_cast<const __half2*>(&u.y);
    const float2 f0 = __half22float2(h0);
    const float2 f1 = __half22float2(h1);
    return make_float4(f0.x, f0.y, f1.x, f1.y);
}
__device__ __forceinline__ void st_h4(__half* p, float4 v) {
    __half2 h0 = __floats2half2_rn(v.x, v.y);
    __half2 h1 = __floats2half2_rn(v.z, v.w);
    uint2 u;
    u.x = *reinterpret_cast<unsigned int*>(&h0);
    u.y = *reinterpret_cast<unsigned int*>(&h1);
    *reinterpret_cast<uint2*>(p) = u;
}
__device__ __forceinline__ void add4(float4& a, const float4 b) {
    a.x += b.x; a.y += b.y; a.z += b.z; a.w += b.w;
}

// ---------------------------------------------------------------------------
// K1 (fused): blocks 0..255 = GEMM1 (h1 = x@W1); blocks 256..8447 = adjacency
// scan (1 row/block). GEMM blocks dispatch first, hide under the 268 MB
// HBM-bound scan (~41us floor).
// ---------------------------------------------------------------------------
__global__ __launch_bounds__(256) void scan_gemm_kernel(
    const float* __restrict__ adj, const float* __restrict__ x,
    const float* __restrict__ W1,
    u16* __restrict__ ell, int* __restrict__ nnz,
    float* __restrict__ dinv, float* __restrict__ arow,
    float* __restrict__ h1)
{
    if (blockIdx.x < 256) {
        const int tx = threadIdx.x & 31;
        const int ty = threadIdx.x >> 5;
        const int c  = tx * 4;
        const int r0 = blockIdx.x * 32 + ty * 4;
        const float4* W4 = reinterpret_cast<const float4*>(W1);
        const float4* xr[4];
        #pragma unroll
        for (int i = 0; i < 4; ++i)
            xr[i] = reinterpret_cast<const float4*>(x + (size_t)(r0 + i) * F_IN);
        float4 acc[4] = {{0,0,0,0},{0,0,0,0},{0,0,0,0},{0,0,0,0}};
        #pragma unroll 2
        for (int kk = 0; kk < F_IN / 4; ++kk) {
            const int k = kk * 4;
            const float4 w0 = W4[(size_t)(k + 0) * 32 + tx];
            const float4 w1 = W4[(size_t)(k + 1) * 32 + tx];
            const float4 w2 = W4[(size_t)(k + 2) * 32 + tx];
            const float4 w3 = W4[(size_t)(k + 3) * 32 + tx];
            #pragma unroll
            for (int i = 0; i < 4; ++i) {
                const float4 xv = xr[i][kk];
                acc[i].x = fmaf(xv.x, w0.x, acc[i].x);
                acc[i].y = fmaf(xv.x, w0.y, acc[i].y);
                acc[i].z = fmaf(xv.x, w0.z, acc[i].z);
                acc[i].w = fmaf(xv.x, w0.w, acc[i].w);
                acc[i].x = fmaf(xv.y, w1.x, acc[i].x);
                acc[i].y = fmaf(xv.y, w1.y, acc[i].y);
                acc[i].z = fmaf(xv.y, w1.z, acc[i].z);
                acc[i].w = fmaf(xv.y, w1.w, acc[i].w);
                acc[i].x = fmaf(xv.z, w2.x, acc[i].x);
                acc[i].y = fmaf(xv.z, w2.y, acc[i].y);
                acc[i].z = fmaf(xv.z, w2.z, acc[i].z);
                acc[i].w = fmaf(xv.z, w2.w, acc[i].w);
                acc[i].x = fmaf(xv.w, w3.x, acc[i].x);
                acc[i].y = fmaf(xv.w, w3.y, acc[i].y);
                acc[i].z = fmaf(xv.w, w3.z, acc[i].z);
                acc[i].w = fmaf(xv.w, w3.w, acc[i].w);
            }
        }
        #pragma unroll
        for (int i = 0; i < 4; ++i)
            *reinterpret_cast<float4*>(h1 + (size_t)(r0 + i) * HID + c) = acc[i];
    } else {
        const int r = blockIdx.x - 256;
        __shared__ int cnt;
        if (threadIdx.x == 0) cnt = 0;
        __syncthreads();
        const uint4* row4 = reinterpret_cast<const uint4*>(adj + (size_t)r * N_NODES);
        u16* __restrict__ erow = ell + (size_t)r * MAX_ELL;
        for (int b = threadIdx.x; b < N_NODES / 4; b += blockDim.x) {
            const uint4 v = row4[b];
            const int base = b * 4;
            if (v.x) { int p = atomicAdd(&cnt, 1); if (p < MAX_ELL) erow[p] = (u16)(base + 0); }
            if (v.y) { int p = atomicAdd(&cnt, 1); if (p < MAX_ELL) erow[p] = (u16)(base + 1); }
            if (v.z) { int p = atomicAdd(&cnt, 1); if (p < MAX_ELL) erow[p] = (u16)(base + 2); }
            if (v.w) { int p = atomicAdd(&cnt, 1); if (p < MAX_ELL) erow[p] = (u16)(base + 3); }
        }
        __syncthreads();
        if (threadIdx.x == 0) {
            int c = cnt; if (c > MAX_ELL) c = MAX_ELL;
            nnz[r] = c;
            const float di = rsqrtf((float)cnt + 1.0f);
            dinv[r] = di;
            arow[r] = C_PROP * di * di;
        }
    }
}

// ---------------------------------------------------------------------------
// K2: s0 = dinv*h1 (fp16), hb = cres*dinv*h1 (fp32). Elementwise.
// ---------------------------------------------------------------------------
__global__ __launch_bounds__(256) void prep1_kernel(
    const float* __restrict__ h1, const float* __restrict__ dinv,
    __half* __restrict__ s0, float* __restrict__ hb)
{
    const int tx = threadIdx.x & 31;
    const int r  = blockIdx.x * 8 + (threadIdx.x >> 5);
    const int c  = tx * 4;
    const size_t o = (size_t)r * HID + c;
    const float di = dinv[r];
    const float4 hv = *reinterpret_cast<const float4*>(h1 + o);
    float4 sv = make_float4(di * hv.x, di * hv.y, di * hv.z, di * hv.w);
    st_h4(s0 + o, sv);
    *reinterpret_cast<float4*>(hb + o) =
        make_float4(C_RES * sv.x, C_RES * sv.y, C_RES * sv.z, C_RES * sv.w);
}

// ---------------------------------------------------------------------------
// K3: layer-1 diffusion step, prescaled fp16 space, 4-way unrolled gathers.
// thread = 1 row x 4 cols; 32 lanes/row; 8 rows/block.
// ---------------------------------------------------------------------------
__global__ __launch_bounds__(256) void diffuse1_kernel(
    const __half* __restrict__ sin, const float* __restrict__ hb,
    __half* __restrict__ sout,
    const u16* __restrict__ ell, const int* __restrict__ nnz,
    const float* __restrict__ arow)
{
    const int tx = threadIdx.x & 31;
    const int r  = blockIdx.x * 8 + (threadIdx.x >> 5);
    const int c  = tx * 4;
    const int nn = nnz[r];
    const u16* __restrict__ erow = ell + (size_t)r * MAX_ELL;

    const float4 hv = *reinterpret_cast<const float4*>(hb + (size_t)r * HID + c);
    float4 a0 = ld_h4(sin + (size_t)r * HID + c);   // self term
    float4 a1 = {0,0,0,0}, a2 = {0,0,0,0}, a3 = {0,0,0,0};
    int t = 0;
    for (; t + 4 <= nn; t += 4) {
        const int j0 = erow[t + 0];
        const int j1 = erow[t + 1];
        const int j2 = erow[t + 2];
        const int j3 = erow[t + 3];
        const float4 g0 = ld_h4(sin + (size_t)j0 * HID + c);
        const float4 g1 = ld_h4(sin + (size_t)j1 * HID + c);
        const float4 g2 = ld_h4(sin + (size_t)j2 * HID + c);
        const float4 g3 = ld_h4(sin + (size_t)j3 * HID + c);
        add4(a0, g0); add4(a1, g1); add4(a2, g2); add4(a3, g3);
    }
    for (; t < nn; ++t) add4(a1, ld_h4(sin + (size_t)erow[t] * HID + c));
    add4(a0, a1); add4(a2, a3); add4(a0, a2);

    const float Ai = arow[r];
    float4 s = make_float4(fmaf(Ai, a0.x, hv.x), fmaf(Ai, a0.y, hv.y),
                           fmaf(Ai, a0.z, hv.z), fmaf(Ai, a0.w, hv.w));
    st_h4(sout + (size_t)r * HID + c, s);
}

// ---------------------------------------------------------------------------
// K4 (merged final1 + gemm2): per row r,
//   o1_c = relu(cprop*dinv_r*G_c + cres*h1_c + b1_c)     (kept in regs)
//   h2[r][:] = o1_row @ W2  via per-lane partials + 5-step shfl_xor butterfly
//   (32 lanes/row; masks 1..16 stay within each 32-lane half of the wave).
// Epilogue lanes 0..15 write h2, s2 = dinv*h2, hb2 = cres*dinv*h2.
// ---------------------------------------------------------------------------
__global__ __launch_bounds__(256) void final1_gemm_kernel(
    const __half* __restrict__ sin, const float* __restrict__ h1,
    const float* __restrict__ b1, const float* __restrict__ W2,
    const u16* __restrict__ ell, const int* __restrict__ nnz,
    const float* __restrict__ dinv,
    float* __restrict__ h2, float* __restrict__ s2, float* __restrict__ hb2)
{
    const int tx = threadIdx.x & 31;
    const int r  = blockIdx.x * 8 + (threadIdx.x >> 5);
    const int c  = tx * 4;
    const int nn = nnz[r];
    const u16* __restrict__ erow = ell + (size_t)r * MAX_ELL;

    float4 a0 = ld_h4(sin + (size_t)r * HID + c);
    float4 a1 = {0,0,0,0}, a2 = {0,0,0,0}, a3 = {0,0,0,0};
    int t = 0;
    for (; t + 4 <= nn; t += 4) {
        const int j0 = erow[t + 0];
        const int j1 = erow[t + 1];
        const int j2 = erow[t + 2];
        const int j3 = erow[t + 3];
        const float4 g0 = ld_h4(sin + (size_t)j0 * HID + c);
        const float4 g1 = ld_h4(sin + (size_t)j1 * HID + c);
        const float4 g2 = ld_h4(sin + (size_t)j2 * HID + c);
        const float4 g3 = ld_h4(sin + (size_t)j3 * HID + c);
        add4(a0, g0); add4(a1, g1); add4(a2, g2); add4(a3, g3);
    }
    for (; t < nn; ++t) add4(a1, ld_h4(sin + (size_t)erow[t] * HID + c));
    add4(a0, a1); add4(a2, a3); add4(a0, a2);

    const float di = dinv[r];
    const float pd = C_PROP * di;
    const float4 hv = *reinterpret_cast<const float4*>(h1 + (size_t)r * HID + c);
    const float4 bv = *reinterpret_cast<const float4*>(b1 + c);
    float ov[4];
    ov[0] = fmaxf(fmaf(pd, a0.x, C_RES * hv.x) + bv.x, 0.f);
    ov[1] = fmaxf(fmaf(pd, a0.y, C_RES * hv.y) + bv.y, 0.f);
    ov[2] = fmaxf(fmaf(pd, a0.z, C_RES * hv.z) + bv.z, 0.f);
    ov[3] = fmaxf(fmaf(pd, a0.w, C_RES * hv.w) + bv.w, 0.f);

    // per-lane partial dot products over this lane's 4 k-indices
    float p[NCLS];
    #pragma unroll
    for (int cc = 0; cc < NCLS; ++cc) p[cc] = 0.f;
    #pragma unroll
    for (int i = 0; i < 4; ++i) {
        const float* w = W2 + (size_t)(c + i) * NCLS;
        const float v = ov[i];
        #pragma unroll
        for (int cc = 0; cc < NCLS; ++cc) p[cc] = fmaf(v, w[cc], p[cc]);
    }
    // butterfly sum across the 32 lanes of this row group
    #pragma unroll
    for (int m = 1; m <= 16; m <<= 1) {
        #pragma unroll
        for (int cc = 0; cc < NCLS; ++cc) p[cc] += __shfl_xor(p[cc], m);
    }
    if (tx < NCLS) {
        const float v = p[tx];
        const size_t o = (size_t)r * NCLS + tx;
        h2[o]  = v;
        s2[o]  = di * v;
        hb2[o] = C_RES * di * v;
    }
}

// ---------------------------------------------------------------------------
// K5: layer-2 diffusion step (fp32, 16 cols = 4 lanes x float4, 64 rows/blk)
// ---------------------------------------------------------------------------
__global__ __launch_bounds__(256) void diffuse2_kernel(
    const float* __restrict__ sin, const float* __restrict__ hb2,
    float* __restrict__ sout,
    const u16* __restrict__ ell, const int* __restrict__ nnz,
    const float* __restrict__ arow)
{
    const int l4 = threadIdx.x & 3;
    const int r  = blockIdx.x * 64 + (threadIdx.x >> 2);
    const int c  = l4 * 4;
    const int nn = nnz[r];
    const u16* __restrict__ erow = ell + (size_t)r * MAX_ELL;

    float4 a0 = *reinterpret_cast<const float4*>(sin + (size_t)r * NCLS + c);
    float4 a1 = {0.f, 0.f, 0.f, 0.f};
    int t = 0;
    for (; t + 2 <= nn; t += 2) {
        const int j0 = erow[t];
        const int j1 = erow[t + 1];
        add4(a0, *reinterpret_cast<const float4*>(sin + (size_t)j0 * NCLS + c));
        add4(a1, *reinterpret_cast<const float4*>(sin + (size_t)j1 * NCLS + c));
    }
    if (t < nn)
        add4(a0, *reinterpret_cast<const float4*>(sin + (size_t)erow[t] * NCLS + c));
    add4(a0, a1);

    const float Ai = arow[r];
    const float4 hv = *reinterpret_cast<const float4*>(hb2 + (size_t)r * NCLS + c);
    float4 s = make_float4(fmaf(Ai, a0.x, hv.x), fmaf(Ai, a0.y, hv.y),
                           fmaf(Ai, a0.z, hv.z), fmaf(Ai, a0.w, hv.w));
    *reinterpret_cast<float4*>(sout + (size_t)r * NCLS + c) = s;
}

// ---------------------------------------------------------------------------
// K6: layer-2 final fused with log_softmax (quad shfl reduce).
// ---------------------------------------------------------------------------
__global__ __launch_bounds__(256) void final2_lsm_kernel(
    const float* __restrict__ sin, const float* __restrict__ h2,
    const float* __restrict__ b2, float* __restrict__ out,
    const u16* __restrict__ ell, const int* __restrict__ nnz,
    const float* __restrict__ dinv)
{
    const int l4 = threadIdx.x & 3;
    const int r  = blockIdx.x * 64 + (threadIdx.x >> 2);
    const int c  = l4 * 4;
    const int nn = nnz[r];
    const u16* __restrict__ erow = ell + (size_t)r * MAX_ELL;

    float4 a0 = *reinterpret_cast<const float4*>(sin + (size_t)r * NCLS + c);
    float4 a1 = {0.f, 0.f, 0.f, 0.f};
    int t = 0;
    for (; t + 2 <= nn; t += 2) {
        const int j0 = erow[t];
        const int j1 = erow[t + 1];
        add4(a0, *reinterpret_cast<const float4*>(sin + (size_t)j0 * NCLS + c));
        add4(a1, *reinterpret_cast<const float4*>(sin + (size_t)j1 * NCLS + c));
    }
    if (t < nn)
        add4(a0, *reinterpret_cast<const float4*>(sin + (size_t)erow[t] * NCLS + c));
    add4(a0, a1);

    const float pd = C_PROP * dinv[r];
    const float4 hv = *reinterpret_cast<const float4*>(h2 + (size_t)r * NCLS + c);
    const float4 bv = *reinterpret_cast<const float4*>(b2 + c);
    float4 o;
    o.x = fmaf(pd, a0.x, C_RES * hv.x) + bv.x;
    o.y = fmaf(pd, a0.y, C_RES * hv.y) + bv.y;
    o.z = fmaf(pd, a0.z, C_RES * hv.z) + bv.z;
    o.w = fmaf(pd, a0.w, C_RES * hv.w) + bv.w;

    float mx = fmaxf(fmaxf(o.x, o.y), fmaxf(o.z, o.w));
    mx = fmaxf(mx, __shfl_xor(mx, 1));
    mx = fmaxf(mx, __shfl_xor(mx, 2));
    float s = __expf(o.x - mx) + __expf(o.y - mx) + __expf(o.z - mx) + __expf(o.w - mx);
    s += __shfl_xor(s, 1);
    s += __shfl_xor(s, 2);
    const float lse = mx + __logf(s);
    *reinterpret_cast<float4*>(out + (size_t)r * NCLS + c) =
        make_float4(o.x - lse, o.y - lse, o.z - lse, o.w - lse);
}

// ---------------------------------------------------------------------------
extern "C" void kernel_launch(void* const* d_in, const int* in_sizes, int n_in,
                              void* d_out, int out_size, void* d_ws, size_t ws_size,
                              hipStream_t stream)
{
    const float* x   = (const float*)d_in[0];
    const float* adj = (const float*)d_in[1];
    const float* W1  = (const float*)d_in[2];
    const float* b1  = (const float*)d_in[3];
    const float* W2  = (const float*)d_in[4];
    const float* b2  = (const float*)d_in[5];
    float* out = (float*)d_out;

    char* ws = (char*)d_ws;
    size_t off = 0;
    auto carve = [&](size_t bytes) -> void* {
        void* p = ws + off;
        off += (bytes + 255) & ~(size_t)255;
        return p;
    };
    u16*    ell  = (u16*)   carve((size_t)N_NODES * MAX_ELL * sizeof(u16));
    int*    nnz  = (int*)   carve((size_t)N_NODES * sizeof(int));
    float*  dinv = (float*) carve((size_t)N_NODES * sizeof(float));
    float*  arow = (float*) carve((size_t)N_NODES * sizeof(float));
    float*  h1   = (float*) carve((size_t)N_NODES * HID * sizeof(float));
    float*  hb   = (float*) carve((size_t)N_NODES * HID * sizeof(float));
    __half* sA   = (__half*)carve((size_t)N_NODES * HID * sizeof(__half));
    __half* sB   = (__half*)carve((size_t)N_NODES * HID * sizeof(__half));
    float*  h2   = (float*) carve((size_t)N_NODES * NCLS * sizeof(float));
    float*  hb2  = (float*) carve((size_t)N_NODES * NCLS * sizeof(float));
    float*  s2A  = (float*) carve((size_t)N_NODES * NCLS * sizeof(float));
    float*  s2B  = (float*) carve((size_t)N_NODES * NCLS * sizeof(float));

    // K1: fused adjacency scan + GEMM1 (GEMM hides under HBM-bound scan)
    scan_gemm_kernel<<<8448, 256, 0, stream>>>(adj, x, W1, ell, nnz, dinv, arow, h1);

    // K2: prep s0/hb (needs dinv -> after scan)
    prep1_kernel<<<N_NODES / 8, 256, 0, stream>>>(h1, dinv, sA, hb);

    // layer-1: 7 fp16 diffusion steps, then merged final+gemm2
    {
        const __half* cur = sA;
        __half* bufs[2] = {sB, sA};
        for (int s = 0; s < 7; ++s) {
            __half* dst = bufs[s & 1];
            diffuse1_kernel<<<N_NODES / 8, 256, 0, stream>>>(cur, hb, dst, ell, nnz, arow);
            cur = dst;
        }
        final1_gemm_kernel<<<N_NODES / 8, 256, 0, stream>>>(
            cur, h1, b1, W2, ell, nnz, dinv, h2, s2A, hb2);
    }

    // layer-2: 7 fp32 diffusion steps + final/lsm (kernel boundary = cheap
    // grid barrier; R1 measured custom spin barrier at ~38us/barrier)
    {
        const float* cur = s2A;
        float* bufs[2] = {s2B, s2A};
        for (int s = 0; s < 7; ++s) {
            float* dst = bufs[s & 1];
            diffuse2_kernel<<<N_NODES / 64, 256, 0, stream>>>(cur, hb2, dst, ell, nnz, arow);
            cur = dst;
        }
        final2_lsm_kernel<<<N_NODES / 64, 256, 0, stream>>>(cur, h2, b2, out, ell, nnz, dinv);
    }
    (void)in_sizes; (void)n_in; (void)out_size; (void)ws_size;
}